// Round 2
// baseline (241.559 us; speedup 1.0000x reference)
//
#include <hip/hip_runtime.h>

// TT embedding lookup, grouped by (table, i1) to read each core1 row once.
// P=(216,216,216), Q=(2,4,2), R=(128,128), tables=2, batch=1024.
// core0: [2,216,256]   (A row:  [Q0=2][R0=128])
// core1: [2,216,65536] (Bm row: [R0=128][S=512], S = q1*128 + r1)
// core2: [2,216,256]   (C row:  [R1=128][Q2=2])
// out:   [2,1024,16]
//
// d_ws int layout:
//   [0,432)      group start offsets
//   [432,864)    group counts
//   [864,2912)   sorted lookup ids (counting sort by group)
//   [2912,4960)  per-lookup aux: (i0<<16)|i2

#define NGROUPS 432   // 2 tables * 216 i1 values
#define NLOOK   2048

__global__ __launch_bounds__(512) void tt_prep(const int* __restrict__ idx32,
                                               int* __restrict__ w) {
    __shared__ int cnt[NGROUPS];
    __shared__ int scan[512];
    __shared__ int cursor[NGROUPS];
    const int tid = threadIdx.x;

    for (int i = tid; i < NGROUPS; i += 512) cnt[i] = 0;
    __syncthreads();

    // int64-vs-int32 buffer detection (values < 2^31 => odd words zero in LE int64)
    const bool is64 = (idx32[1] == 0) & (idx32[3] == 0) &
                      (idx32[5] == 0) & (idx32[7] == 0);

    int grp[4];
#pragma unroll
    for (int j = 0; j < 4; ++j) {
        const int id = tid + j * 512;                 // coalesced over block
        const unsigned idx = is64 ? (unsigned)((const long long*)idx32)[id]
                                  : (unsigned)idx32[id];
        const unsigned i0  = idx / 46656u;
        const unsigned rem = idx - i0 * 46656u;
        const unsigned i1  = rem / 216u;
        const unsigned i2  = rem - i1 * 216u;
        const int table = id >> 10;
        grp[j] = table * 216 + (int)i1;
        w[2912 + id] = (int)((i0 << 16) | i2);
        atomicAdd(&cnt[grp[j]], 1);
    }
    __syncthreads();

    // Hillis-Steele inclusive scan over 512 slots (>= NGROUPS)
    scan[tid] = (tid < NGROUPS) ? cnt[tid] : 0;
    __syncthreads();
    for (int off = 1; off < 512; off <<= 1) {
        const int v   = scan[tid];
        const int add = (tid >= off) ? scan[tid - off] : 0;
        __syncthreads();
        scan[tid] = v + add;
        __syncthreads();
    }
    if (tid < NGROUPS) {
        const int st = scan[tid] - cnt[tid];   // exclusive
        w[tid]        = st;
        w[432 + tid]  = cnt[tid];
        cursor[tid]   = st;
    }
    __syncthreads();

#pragma unroll
    for (int j = 0; j < 4; ++j) {
        const int id  = tid + j * 512;
        const int pos = atomicAdd(&cursor[grp[j]], 1);
        w[864 + pos] = id;
    }
}

// One block per (group, column-half). 64 threads; thread owns 4 consecutive
// columns of its half (float4 per row). Processes up to 8 lookups per pass,
// reading the group's Bm row-half exactly once per pass.
__global__ __launch_bounds__(64) void tt_main(
    const float* __restrict__ c0,
    const float* __restrict__ c1,
    const float* __restrict__ c2,
    const int* __restrict__ w,
    float* __restrict__ out)
{
    const int g = blockIdx.x;       // group id [0,432)
    const int h = blockIdx.y;       // column half {0,1}
    const int m = w[432 + g];
    if (m == 0) return;
    const int s0    = w[g];
    const int table = g / 216;
    const int i1    = g - table * 216;
    const int tl    = threadIdx.x;

    // this thread's 4 columns: col = h*256 + 4*tl
    const float4* b4 = (const float4*)(c1 + (((size_t)table * 216 + i1) << 16))
                       + (h * 64 + tl);

    __shared__ float A[8][256];     // A[l][2*r + q0] (interleaved for float2 reads)
    __shared__ int   s_id[8];
    __shared__ int   s_aux[8];

    for (int base = 0; base < m; base += 8) {
        const int cl = min(8, m - base);
        __syncthreads();            // protect LDS rewrite vs previous pass
        if (tl < 8) {
            const bool ok = tl < cl;
            const int id  = ok ? w[864 + s0 + base + tl] : 0;
            s_id[tl]  = id;
            s_aux[tl] = ok ? w[2912 + id] : -1;
        }
        __syncthreads();

        // stage A rows into LDS, transposed to [r][q0] interleave; zero padding
#pragma unroll
        for (int l = 0; l < 8; ++l) {
            const int aux = s_aux[l];
            if (aux >= 0) {
                const float* ar = c0 + ((size_t)table * 216 + (aux >> 16)) * 256;
#pragma unroll
                for (int k = 0; k < 4; ++k) {
                    const int e = tl + 64 * k;             // 0..255
                    A[l][e] = ar[((e & 1) << 7) + (e >> 1)];
                }
            } else {
#pragma unroll
                for (int k = 0; k < 4; ++k) A[l][tl + 64 * k] = 0.f;
            }
        }
        __syncthreads();

        float4 acc[8][2];
#pragma unroll
        for (int l = 0; l < 8; ++l) {
            acc[l][0] = make_float4(0.f, 0.f, 0.f, 0.f);
            acc[l][1] = make_float4(0.f, 0.f, 0.f, 0.f);
        }

#pragma unroll 8
        for (int r = 0; r < 128; ++r) {
            const float4 bv = b4[(size_t)r * 128];
#pragma unroll
            for (int l = 0; l < 8; ++l) {
                const float2 av = ((const float2*)A[l])[r];  // (a_q0=0, a_q0=1), broadcast
                acc[l][0].x += av.x * bv.x; acc[l][0].y += av.x * bv.y;
                acc[l][0].z += av.x * bv.z; acc[l][0].w += av.x * bv.w;
                acc[l][1].x += av.y * bv.x; acc[l][1].y += av.y * bv.y;
                acc[l][1].z += av.y * bv.z; acc[l][1].w += av.y * bv.w;
            }
        }

        // stage 2: contract with per-lookup C, butterfly over 32-lane groups
        const int q1 = 2 * h + (tl >> 5);
        const int r1 = (tl & 31) * 4;
#pragma unroll
        for (int l = 0; l < 8; ++l) {
            if (l < cl) {
                const int aux = s_aux[l];
                const float* crow = c2 + ((size_t)table * 216 + (aux & 0xffff)) * 256;
                const float4 cA = *(const float4*)(crow + r1 * 2);
                const float4 cB = *(const float4*)(crow + r1 * 2 + 4);
                float p00 = acc[l][0].x*cA.x + acc[l][0].y*cA.z + acc[l][0].z*cB.x + acc[l][0].w*cB.z;
                float p01 = acc[l][0].x*cA.y + acc[l][0].y*cA.w + acc[l][0].z*cB.y + acc[l][0].w*cB.w;
                float p10 = acc[l][1].x*cA.x + acc[l][1].y*cA.z + acc[l][1].z*cB.x + acc[l][1].w*cB.z;
                float p11 = acc[l][1].x*cA.y + acc[l][1].y*cA.w + acc[l][1].z*cB.y + acc[l][1].w*cB.w;
#pragma unroll
                for (int mm = 16; mm >= 1; mm >>= 1) {
                    p00 += __shfl_xor(p00, mm);
                    p01 += __shfl_xor(p01, mm);
                    p10 += __shfl_xor(p10, mm);
                    p11 += __shfl_xor(p11, mm);
                }
                if ((tl & 31) == 0) {
                    float* o = out + (size_t)s_id[l] * 16;
                    o[q1 * 2 + 0]     = p00;
                    o[q1 * 2 + 1]     = p01;
                    o[8 + q1 * 2 + 0] = p10;
                    o[8 + q1 * 2 + 1] = p11;
                }
            }
        }
    }
}

extern "C" void kernel_launch(void* const* d_in, const int* in_sizes, int n_in,
                              void* d_out, int out_size, void* d_ws, size_t ws_size,
                              hipStream_t stream) {
    const int*   idx = (const int*)d_in[0];
    const float* c0  = (const float*)d_in[1];
    const float* c1  = (const float*)d_in[2];
    const float* c2  = (const float*)d_in[3];
    float* out = (float*)d_out;
    int* w = (int*)d_ws;

    tt_prep<<<dim3(1), dim3(512), 0, stream>>>(idx, w);
    tt_main<<<dim3(NGROUPS, 2), dim3(64), 0, stream>>>(c0, c1, c2, w, out);
}

// Round 3
// 183.662 us; speedup vs baseline: 1.3152x; 1.3152x over previous
//
#include <hip/hip_runtime.h>

// TT embedding lookup, grouped by (table, i1) so each core1 row is read ~once.
// P=(216,216,216), Q=(2,4,2), R=(128,128), tables=2, batch=1024.
// core0: [2,216,256]   (A row:  [Q0=2][R0=128])
// core1: [2,216,65536] (Bm row: [R0=128][S=512], S = q1*128 + r1)
// core2: [2,216,256]   (C row:  [R1=128][Q2=2])
// out:   [2,1024,16]
//
// d_ws int layout:
//   [0,432)      group start offsets
//   [432,864)    group counts
//   [864,2912)   sorted lookup ids (counting sort by group)
//   [2912,4960)  per-lookup aux: (i0<<16)|i2
//
// tt_main grid: (432 groups, 2 column-halves, 2 chunk-slots), 128 threads
// (2 waves, r-split: wave0 r<64, wave1 r>=64; LDS combine). Chunk = 8 lookups.

#define NGROUPS 432
#define NLOOK   2048

__global__ __launch_bounds__(512) void tt_prep(const int* __restrict__ idx32,
                                               int* __restrict__ w) {
    __shared__ int cnt[NGROUPS];
    __shared__ int scan[512];
    __shared__ int cursor[NGROUPS];
    const int tid = threadIdx.x;

    for (int i = tid; i < NGROUPS; i += 512) cnt[i] = 0;
    __syncthreads();

    // int64-vs-int32 buffer detection (values < 2^31 => odd words zero in LE int64)
    const bool is64 = (idx32[1] == 0) & (idx32[3] == 0) &
                      (idx32[5] == 0) & (idx32[7] == 0);

    int grp[4];
#pragma unroll
    for (int j = 0; j < 4; ++j) {
        const int id = tid + j * 512;
        const unsigned idx = is64 ? (unsigned)((const long long*)idx32)[id]
                                  : (unsigned)idx32[id];
        const unsigned i0  = idx / 46656u;
        const unsigned rem = idx - i0 * 46656u;
        const unsigned i1  = rem / 216u;
        const unsigned i2  = rem - i1 * 216u;
        const int table = id >> 10;
        grp[j] = table * 216 + (int)i1;
        w[2912 + id] = (int)((i0 << 16) | i2);
        atomicAdd(&cnt[grp[j]], 1);
    }
    __syncthreads();

    scan[tid] = (tid < NGROUPS) ? cnt[tid] : 0;
    __syncthreads();
    for (int off = 1; off < 512; off <<= 1) {
        const int v   = scan[tid];
        const int add = (tid >= off) ? scan[tid - off] : 0;
        __syncthreads();
        scan[tid] = v + add;
        __syncthreads();
    }
    if (tid < NGROUPS) {
        const int st = scan[tid] - cnt[tid];
        w[tid]        = st;
        w[432 + tid]  = cnt[tid];
        cursor[tid]   = st;
    }
    __syncthreads();

#pragma unroll
    for (int j = 0; j < 4; ++j) {
        const int id  = tid + j * 512;
        const int pos = atomicAdd(&cursor[grp[j]], 1);
        w[864 + pos] = id;
    }
}

__global__ __launch_bounds__(128) void tt_main(
    const float* __restrict__ c0,
    const float* __restrict__ c1,
    const float* __restrict__ c2,
    const int* __restrict__ w,
    float* __restrict__ out)
{
    const int g = blockIdx.x;       // group id [0,432)
    const int h = blockIdx.y;       // column half {0,1}
    const int cs = blockIdx.z;      // chunk slot {0,1}
    const int m = w[432 + g];
    if (m <= cs * 8) return;
    const int s0    = w[g];
    const int table = g / 216;
    const int i1    = g - table * 216;

    const int tid = threadIdx.x;
    const int wv  = tid >> 6;       // wave: 0 handles r<64, 1 handles r>=64
    const int tl  = tid & 63;

    // comb: 16 KB. During the FMA loop its first 8 KB alias the A staging
    // buffer (A[l][256], [r][q0]-interleaved); after the loop wave1 dumps its
    // partial accumulators here for the r-split combine.
    __shared__ float comb[4096];
    float4* comb4 = (float4*)comb;
    __shared__ int s_id[8];
    __shared__ int s_aux[8];

    // this thread's 4 columns: col = h*256 + 4*tl, rows r = wv*64 + rr
    const float4* b4 = (const float4*)(c1 + (((size_t)table * 216 + i1) << 16))
                       + (h * 64 + tl) + (size_t)(wv * 64) * 128;

    for (int base = cs * 8; base < m; base += 16) {
        const int cl = min(8, m - base);
        __syncthreads();            // protect LDS rewrite vs previous pass
        if (tid < 8) {
            const bool ok = tid < cl;
            const int id  = ok ? w[864 + s0 + base + tid] : 0;
            s_id[tid]  = id;
            s_aux[tid] = ok ? w[2912 + id] : -1;
        }
        __syncthreads();

        // stage A rows into LDS [r][q0]-interleaved; 128 threads x 2 elems/l
#pragma unroll
        for (int l = 0; l < 8; ++l) {
            const int aux = s_aux[l];
            const float* ar = c0 + ((size_t)table * 216 + (aux >> 16)) * 256;
#pragma unroll
            for (int k = 0; k < 2; ++k) {
                const int e = tid + 128 * k;           // 0..255
                comb[l * 256 + e] = (aux >= 0) ? ar[((e & 1) << 7) + (e >> 1)] : 0.f;
            }
        }
        __syncthreads();

        float4 acc[8][2];
#pragma unroll
        for (int l = 0; l < 8; ++l) {
            acc[l][0] = make_float4(0.f, 0.f, 0.f, 0.f);
            acc[l][1] = make_float4(0.f, 0.f, 0.f, 0.f);
        }

#pragma unroll 8
        for (int rr = 0; rr < 64; ++rr) {
            const float4 bv = b4[(size_t)rr * 128];
            const int r = wv * 64 + rr;
#pragma unroll
            for (int l = 0; l < 8; ++l) {
                const float2 av = ((const float2*)(comb + l * 256))[r];  // broadcast
                acc[l][0].x += av.x * bv.x; acc[l][0].y += av.x * bv.y;
                acc[l][0].z += av.x * bv.z; acc[l][0].w += av.x * bv.w;
                acc[l][1].x += av.y * bv.x; acc[l][1].y += av.y * bv.y;
                acc[l][1].z += av.y * bv.z; acc[l][1].w += av.y * bv.w;
            }
        }

        // r-split combine: wave1 -> LDS (overwrites A region), wave0 adds.
        __syncthreads();            // all A reads done before overwrite
        if (wv == 1) {
#pragma unroll
            for (int l = 0; l < 8; ++l) {
                comb4[(l * 2 + 0) * 64 + tl] = acc[l][0];
                comb4[(l * 2 + 1) * 64 + tl] = acc[l][1];
            }
        }
        __syncthreads();

        if (wv == 0) {
            const int q1 = 2 * h + (tl >> 5);
            const int r1 = (tl & 31) * 4;
#pragma unroll
            for (int l = 0; l < 8; ++l) {
                const float4 t0 = comb4[(l * 2 + 0) * 64 + tl];
                const float4 t1 = comb4[(l * 2 + 1) * 64 + tl];
                acc[l][0].x += t0.x; acc[l][0].y += t0.y;
                acc[l][0].z += t0.z; acc[l][0].w += t0.w;
                acc[l][1].x += t1.x; acc[l][1].y += t1.y;
                acc[l][1].z += t1.z; acc[l][1].w += t1.w;
                if (l < cl) {
                    const int aux = s_aux[l];
                    const float* crow = c2 + ((size_t)table * 216 + (aux & 0xffff)) * 256;
                    const float4 cA = *(const float4*)(crow + r1 * 2);
                    const float4 cB = *(const float4*)(crow + r1 * 2 + 4);
                    float p00 = acc[l][0].x*cA.x + acc[l][0].y*cA.z + acc[l][0].z*cB.x + acc[l][0].w*cB.z;
                    float p01 = acc[l][0].x*cA.y + acc[l][0].y*cA.w + acc[l][0].z*cB.y + acc[l][0].w*cB.w;
                    float p10 = acc[l][1].x*cA.x + acc[l][1].y*cA.z + acc[l][1].z*cB.x + acc[l][1].w*cB.z;
                    float p11 = acc[l][1].x*cA.y + acc[l][1].y*cA.w + acc[l][1].z*cB.y + acc[l][1].w*cB.w;
#pragma unroll
                    for (int mm = 16; mm >= 1; mm >>= 1) {
                        p00 += __shfl_xor(p00, mm);
                        p01 += __shfl_xor(p01, mm);
                        p10 += __shfl_xor(p10, mm);
                        p11 += __shfl_xor(p11, mm);
                    }
                    if ((tl & 31) == 0) {
                        float* o = out + (size_t)s_id[l] * 16;
                        o[q1 * 2 + 0]     = p00;
                        o[q1 * 2 + 1]     = p01;
                        o[8 + q1 * 2 + 0] = p10;
                        o[8 + q1 * 2 + 1] = p11;
                    }
                }
            }
        }
    }
}

extern "C" void kernel_launch(void* const* d_in, const int* in_sizes, int n_in,
                              void* d_out, int out_size, void* d_ws, size_t ws_size,
                              hipStream_t stream) {
    const int*   idx = (const int*)d_in[0];
    const float* c0  = (const float*)d_in[1];
    const float* c1  = (const float*)d_in[2];
    const float* c2  = (const float*)d_in[3];
    float* out = (float*)d_out;
    int* w = (int*)d_ws;

    tt_prep<<<dim3(1), dim3(512), 0, stream>>>(idx, w);
    tt_main<<<dim3(NGROUPS, 2, 2), dim3(128), 0, stream>>>(c0, c1, c2, w, out);
}

// Round 4
// 182.850 us; speedup vs baseline: 1.3211x; 1.0044x over previous
//
#include <hip/hip_runtime.h>

// TT embedding lookup, grouped by (table, i1) so each core1 row is read ~once.
// P=(216,216,216), Q=(2,4,2), R=(128,128), tables=2, batch=1024.
// core0: [2,216,256]   (A row:  [Q0=2][R0=128])
// core1: [2,216,65536] (Bm row: [R0=128][S=512], S = q1*128 + r1)
// core2: [2,216,256]   (C row:  [R1=128][Q2=2])
// out:   [2,1024,16]
//
// d_ws int layout:
//   [0,432)      group start offsets
//   [432,864)    group counts
//   [864,2912)   sorted lookup ids (counting sort by group)
//   [2912,4960)  per-lookup aux: (i0<<16)|i2
//
// tt_main grid: (432 groups, 4 s-quarters, 2 chunk-slots) x 128 threads
// (2 waves = r-halves). Lane owns 2 columns (float2): acc[8][2] = 32 VGPRs
// so the unroll-8 load pipeline fits without spills/AGPR traffic.

#define NGROUPS 432
#define NLOOK   2048

__global__ __launch_bounds__(512) void tt_prep(const int* __restrict__ idx32,
                                               int* __restrict__ w) {
    __shared__ int cnt[NGROUPS];
    __shared__ int wtot[8];
    __shared__ int cursor[NGROUPS];
    const int tid  = threadIdx.x;
    const int lane = tid & 63;
    const int wv   = tid >> 6;

    for (int i = tid; i < NGROUPS; i += 512) cnt[i] = 0;
    __syncthreads();

    // int64-vs-int32 buffer detection (values < 2^31 => odd words zero in LE int64)
    const bool is64 = (idx32[1] == 0) & (idx32[3] == 0) &
                      (idx32[5] == 0) & (idx32[7] == 0);

    int grp[4];
#pragma unroll
    for (int j = 0; j < 4; ++j) {
        const int id = tid + j * 512;
        const unsigned idx = is64 ? (unsigned)((const long long*)idx32)[id]
                                  : (unsigned)idx32[id];
        const unsigned i0  = idx / 46656u;
        const unsigned rem = idx - i0 * 46656u;
        const unsigned i1  = rem / 216u;
        const unsigned i2  = rem - i1 * 216u;
        const int table = id >> 10;
        grp[j] = table * 216 + (int)i1;
        w[2912 + id] = (int)((i0 << 16) | i2);
        atomicAdd(&cnt[grp[j]], 1);
    }
    __syncthreads();

    // two-level exclusive scan: shfl wave-scan + wave-total offsets
    const int v = (tid < NGROUPS) ? cnt[tid] : 0;
    int s = v;
#pragma unroll
    for (int d = 1; d < 64; d <<= 1) {
        const int t = __shfl_up(s, d);
        if (lane >= d) s += t;
    }
    if (lane == 63) wtot[wv] = s;
    __syncthreads();
    int off = 0;
    for (int i = 0; i < wv; ++i) off += wtot[i];
    if (tid < NGROUPS) {
        const int st = s + off - v;        // exclusive prefix
        w[tid]       = st;
        w[432 + tid] = v;
        cursor[tid]  = st;
    }
    __syncthreads();

#pragma unroll
    for (int j = 0; j < 4; ++j) {
        const int id  = tid + j * 512;
        const int pos = atomicAdd(&cursor[grp[j]], 1);
        w[864 + pos] = id;
    }
}

__global__ __launch_bounds__(128) void tt_main(
    const float* __restrict__ c0,
    const float* __restrict__ c1,
    const float* __restrict__ c2,
    const int* __restrict__ w,
    float* __restrict__ out)
{
    const int g  = blockIdx.x;      // group id [0,432)
    const int q  = blockIdx.y;      // s-quarter {0..3} == q1
    const int cs = blockIdx.z;      // chunk slot {0,1}
    const int m = w[432 + g];
    if (m <= cs * 8) return;
    const int s0    = w[g];
    const int table = g / 216;
    const int i1    = g - table * 216;

    const int tid = threadIdx.x;
    const int rh  = tid >> 6;       // r-half: wave0 r<64, wave1 r>=64
    const int tl  = tid & 63;

    // 8 KB LDS, dual-purpose: A staging ([l][2r+q0] interleave) during the
    // FMA loop; wave1's partial accumulators during the r-split combine.
    __shared__ float lds[2048];
    float2* lds2 = (float2*)lds;
    __shared__ int s_id[8];
    __shared__ int s_aux[8];

    // lane owns cols s = 128*q + 2*tl (+1); float2 index into row: r*256 + 64q + tl
    const float2* b2 = (const float2*)(c1 + (((size_t)(table * 216 + i1)) << 16))
                       + (size_t)rh * 64 * 256 + (q * 64 + tl);
    const float* c0t = c0 + (size_t)table * 216 * 256;

    for (int base = cs * 8; base < m; base += 16) {
        const int cl = min(8, m - base);
        __syncthreads();            // previous pass's LDS reads done
        if (tid < 8) {
            const bool ok = tid < cl;
            const int id  = ok ? w[864 + s0 + base + tid] : 0;
            s_id[tid]  = id;
            s_aux[tid] = ok ? w[2912 + id] : 0;   // pad -> row 0 (in-bounds, output gated)
        }
        __syncthreads();

        // stage A: coalesced global read, transposed LDS store (stride-2 = free)
#pragma unroll
        for (int l = 0; l < 8; ++l) {
            const float* ar = c0t + (size_t)(s_aux[l] >> 16) * 256;
#pragma unroll
            for (int k = 0; k < 2; ++k) {
                const int e = tid + 128 * k;              // e = q0*128 + r
                lds[l * 256 + 2 * (e & 127) + (e >> 7)] = ar[e];
            }
        }
        __syncthreads();

        float2 acc[8][2];
#pragma unroll
        for (int l = 0; l < 8; ++l) {
            acc[l][0] = make_float2(0.f, 0.f);
            acc[l][1] = make_float2(0.f, 0.f);
        }

#pragma unroll 8
        for (int rr = 0; rr < 64; ++rr) {
            const float2 bv = b2[(size_t)rr * 256];
            const int r = rh * 64 + rr;
#pragma unroll
            for (int l = 0; l < 8; ++l) {
                const float2 av = lds2[l * 128 + r];   // (A[0][r], A[1][r]) broadcast
                acc[l][0].x += av.x * bv.x; acc[l][0].y += av.x * bv.y;
                acc[l][1].x += av.y * bv.x; acc[l][1].y += av.y * bv.y;
            }
        }

        // r-split combine: wave1 -> LDS (overwrites A region), wave0 adds.
        __syncthreads();
        if (rh == 1) {
#pragma unroll
            for (int l = 0; l < 8; ++l) {
                lds2[(l * 2 + 0) * 64 + tl] = acc[l][0];
                lds2[(l * 2 + 1) * 64 + tl] = acc[l][1];
            }
        }
        __syncthreads();

        if (rh == 0) {
#pragma unroll
            for (int l = 0; l < 8; ++l) {
                const float2 t0 = lds2[(l * 2 + 0) * 64 + tl];
                const float2 t1 = lds2[(l * 2 + 1) * 64 + tl];
                const float a0x = acc[l][0].x + t0.x, a0y = acc[l][0].y + t0.y;
                const float a1x = acc[l][1].x + t1.x, a1y = acc[l][1].y + t1.y;
                if (l < cl) {
                    // lane's r1 = 2*tl, 2*tl+1; C[r1][j] at crow[r1*2+j]
                    const float* crow = c2 + (size_t)(table * 216 + (s_aux[l] & 0xffff)) * 256;
                    const float4 cv = *(const float4*)(crow + 4 * tl);
                    float p00 = a0x * cv.x + a0y * cv.z;
                    float p01 = a0x * cv.y + a0y * cv.w;
                    float p10 = a1x * cv.x + a1y * cv.z;
                    float p11 = a1x * cv.y + a1y * cv.w;
#pragma unroll
                    for (int mm = 32; mm >= 1; mm >>= 1) {
                        p00 += __shfl_xor(p00, mm);
                        p01 += __shfl_xor(p01, mm);
                        p10 += __shfl_xor(p10, mm);
                        p11 += __shfl_xor(p11, mm);
                    }
                    if (tl == 0) {
                        float* o = out + (size_t)s_id[l] * 16;
                        o[q * 2 + 0]     = p00;   // (q0=0, q1=q, j)
                        o[q * 2 + 1]     = p01;
                        o[8 + q * 2 + 0] = p10;   // q0=1
                        o[8 + q * 2 + 1] = p11;
                    }
                }
            }
        }
    }
}

extern "C" void kernel_launch(void* const* d_in, const int* in_sizes, int n_in,
                              void* d_out, int out_size, void* d_ws, size_t ws_size,
                              hipStream_t stream) {
    const int*   idx = (const int*)d_in[0];
    const float* c0  = (const float*)d_in[1];
    const float* c1  = (const float*)d_in[2];
    const float* c2  = (const float*)d_in[3];
    float* out = (float*)d_out;
    int* w = (int*)d_ws;

    tt_prep<<<dim3(1), dim3(512), 0, stream>>>(idx, w);
    tt_main<<<dim3(NGROUPS, 4, 2), dim3(128), 0, stream>>>(c0, c1, c2, w, out);
}